// Round 10
// baseline (19346.111 us; speedup 1.0000x reference)
//
#include <hip/hip_runtime.h>
#include <cstdint>
#include <cstddef>

// LSTM T=8192, I=256, H=1024. Persistent, BARRIER-FREE wave-dataflow design:
//  - 64 WGs x 256 threads = 256 waves; wave (wg,w) owns 4 hidden units
//    [wg*16+w*4, +4) -> 16 full gate rows (i,f,g,o x 4 units) x 1280 cols.
//    Row-split (not column-split) => no cross-wave reduction, no barriers:
//    every wave is an independent dataflow actor, self-synchronized purely
//    by the tagged h ring in global memory.
//  - Per lane: row rl=l>>2 (16 rows/wave, 4 lanes each), col chunk q=l&3
//    (320 cols). Weights fp16-packed in 160 VGPRs/lane.
//  - Cross-wave h exchange: SELF-VALIDATING words (fp32 h, 2 mantissa LSBs
//    = t&3). Readers poll data words directly until all tags match; detection
//    IS arrival. Ring depth 2 (slot=t&1, tag=t&3): reader at step t polling
//    t-1 implies no wave is past step t => slot overwrite impossible
//    (same proof as round 1). 0xAA poison = tag 2, alias-free.
//  - Per step per wave: prefetch x[t]; poll 8xu64 of h[t-1]; pack fp16 ->
//    PRIVATE LDS z-slice; s_waitcnt lgkmcnt(0) (wave-internal, NO
//    __syncthreads); 40x broadcast ds_read_b128 + 160 fdot2; quad
//    shfl_xor reduce; 4-shfl gate gather; lanes 0-3 update c, tagged
//    h store. out[t-1] by wave (t-1)&255 from its own z-slice, off-path.

#define T_STEPS 8192
#define IDIM 256
#define HDIM 1024
#define NWG 64
#define TPB 256

typedef _Float16 h2_t __attribute__((ext_vector_type(2)));

#if defined(__has_builtin)
#if __has_builtin(__builtin_amdgcn_fdot2)
#define HAS_FDOT2 1
#endif
#endif

__device__ __forceinline__ float fdot2(uint32_t a, uint32_t b, float c) {
#ifdef HAS_FDOT2
  return __builtin_amdgcn_fdot2(__builtin_bit_cast(h2_t, a),
                                __builtin_bit_cast(h2_t, b), c, false);
#else
  const h2_t av = __builtin_bit_cast(h2_t, a);
  const h2_t bv = __builtin_bit_cast(h2_t, b);
  c = fmaf((float)av[0], (float)bv[0], c);
  c = fmaf((float)av[1], (float)bv[1], c);
  return c;
#endif
}
__device__ __forceinline__ uint32_t packf16(float a, float b) {
  h2_t v;
  v[0] = (_Float16)a;
  v[1] = (_Float16)b;
  return __builtin_bit_cast(uint32_t, v);
}
__device__ __forceinline__ float sigmoidf_(float x) {
  return 1.0f / (1.0f + __expf(-x));
}
__device__ __forceinline__ float tanhf_(float x) {
  return 1.0f - 2.0f / (1.0f + __expf(2.0f * x));
}

__global__ __launch_bounds__(TPB, 1) void lstm_persistent(
    const float* __restrict__ seq, const float* __restrict__ Wih,
    const float* __restrict__ Whh, const float* __restrict__ bih,
    const float* __restrict__ bhh, const float* __restrict__ Wout,
    const float* __restrict__ bout, float* __restrict__ out,
    uint32_t* __restrict__ ring) {
  const int wg = blockIdx.x;
  const int tid = threadIdx.x;
  const int w = tid >> 6;           // wave 0..3 within WG
  const int l = tid & 63;           // lane
  const int gwid = (wg << 2) | w;   // global wave id 0..255

  __shared__ alignas(16) uint32_t zbuf[4][640];  // per-wave private z slices
  __shared__ alignas(16) uint32_t wlds[512];     // W_out fp16 pairs (shared RO)

  // Stage W_out (1024 floats) into LDS as fp16 pairs.
  {
    float4 wv = *(const float4*)(Wout + tid * 4);
    wlds[tid * 2] = packf16(wv.x, wv.y);
    wlds[tid * 2 + 1] = packf16(wv.z, wv.w);
  }
  const float b_out0 = bout[0];

  // Per-lane weights: row rl = l>>2 (gate = rl>>2, unit j = rl&3),
  // col chunk q = l&3 -> cols [320q, 320q+320) of z=[h|x].
  const int rl = l >> 2;
  const int q = l & 3;
  const int grow = (rl >> 2) * HDIM + wg * 16 + w * 4 + (rl & 3);
  const float bias_l = bih[grow] + bhh[grow];
  const float* whrow = Whh + (size_t)grow * HDIM;
  const float* wirow = Wih + (size_t)grow * IDIM;
  const int cbase = q * 320;
  uint32_t wreg[160];
#pragma unroll
  for (int j2 = 0; j2 < 160; ++j2) {
    const int c = cbase + 2 * j2;  // even; never straddles the h|x boundary
    float a, b;
    if (c < HDIM) {
      a = whrow[c];
      b = whrow[c + 1];
    } else {
      a = wirow[c - HDIM];
      b = wirow[c - HDIM + 1];
    }
    wreg[j2] = packf16(a, b);
  }

  __syncthreads();  // wlds ready — the ONLY barrier in this kernel

  uint32_t* const zb = zbuf[w];
  float c_st = 0.0f;  // cell state for unit (l&3); meaningful, stored by l<4
  int dead = 0;       // poll-guard tripped: free-run to avoid harness hang

  for (int t = 0; t <= T_STEPS; ++t) {
    // Prefetch x[t] (independent of h — hides under the poll).
    float4 xv = make_float4(0.f, 0.f, 0.f, 0.f);
    if (t < T_STEPS) xv = *(const float4*)(seq + (size_t)t * IDIM + 4 * l);

    if (t > 0) {
      // Poll this lane's 16 h words of step t-1 (units [16l,16l+16)).
      const uint64_t want = (uint64_t)((t - 1) & 3) * 0x0000000100000001ull;
      const uint64_t msk = 0x0000000300000003ull;
      const uint64_t* hp =
          (const uint64_t*)(ring + ((t - 1) & 1) * HDIM + 16 * l);
      uint64_t v[8] = {0, 0, 0, 0, 0, 0, 0, 0};
      if (!dead) {
        int guard = 0;
        for (;;) {
#pragma unroll
          for (int k = 0; k < 8; ++k)
            v[k] = __hip_atomic_load(hp + k, __ATOMIC_RELAXED,
                                     __HIP_MEMORY_SCOPE_AGENT);
          bool ok = true;
#pragma unroll
          for (int k = 0; k < 8; ++k) ok = ok && ((v[k] & msk) == want);
          if (ok) break;
          if (++guard > (1 << 20)) { dead = 1; break; }
        }
      }
      // Pack 16 fp32 -> 8 u32 fp16 pairs, write private LDS slice.
      uint32_t pk[8];
#pragma unroll
      for (int k = 0; k < 8; ++k)
        pk[k] = packf16(__uint_as_float((uint32_t)v[k]),
                        __uint_as_float((uint32_t)(v[k] >> 32)));
      *(uint4*)(zb + 8 * l) = *(const uint4*)(pk);
      *(uint4*)(zb + 8 * l + 4) = *(const uint4*)(pk + 4);
    } else {
      // h[-1] = 0
      const uint4 z4 = {0u, 0u, 0u, 0u};
      *(uint4*)(zb + 8 * l) = z4;
      *(uint4*)(zb + 8 * l + 4) = z4;
    }
    if (t < T_STEPS) {
      zb[512 + 2 * l] = packf16(xv.x, xv.y);
      zb[512 + 2 * l + 1] = packf16(xv.z, xv.w);
    }
    // Wave-internal cross-lane LDS visibility: wait own DS writes, no barrier.
    asm volatile("s_waitcnt lgkmcnt(0)" ::: "memory");
    __builtin_amdgcn_sched_barrier(0);

    if (t < T_STEPS) {
      // Matvec: rows rl (full 1280 cols via 4-lane quad split).
      float ac0 = 0.f, ac1 = 0.f, ac2 = 0.f, ac3 = 0.f;
      const uint32_t* zs = zb + 160 * q;
#pragma unroll
      for (int k = 0; k < 40; ++k) {
        const uint4 zv = *(const uint4*)(zs + 4 * k);  // 16-lane broadcast
        ac0 = fdot2(wreg[4 * k + 0], zv.x, ac0);
        ac1 = fdot2(wreg[4 * k + 1], zv.y, ac1);
        ac2 = fdot2(wreg[4 * k + 2], zv.z, ac2);
        ac3 = fdot2(wreg[4 * k + 3], zv.w, ac3);
      }
      float s = (ac0 + ac1) + (ac2 + ac3);
      s += __shfl_xor(s, 1);  // quad reduce over col chunks
      s += __shfl_xor(s, 2);
      const float g = s + bias_l;  // all 4 lanes of quad hold row sum
      // Gather i,f,g,o for unit j = l&3 (rows at rl = gate*4+j -> lane 16g+4j).
      const int j = l & 3;
      const float gi = __shfl(g, 4 * j);
      const float gf = __shfl(g, 16 + 4 * j);
      const float gg = __shfl(g, 32 + 4 * j);
      const float go = __shfl(g, 48 + 4 * j);
      const float is = sigmoidf_(gi);
      const float fs = sigmoidf_(gf);
      const float gt = tanhf_(gg);
      const float os = sigmoidf_(go);
      c_st = fs * c_st + is * gt;
      const float hv = os * tanhf_(c_st);
      if (l < 4) {
        // Tagged store: 2 mantissa LSBs carry t&3.
        const uint32_t hb = (__float_as_uint(hv) & ~3u) | (uint32_t)(t & 3);
        __hip_atomic_store(ring + (t & 1) * HDIM + wg * 16 + w * 4 + l, hb,
                           __ATOMIC_RELAXED, __HIP_MEMORY_SCOPE_AGENT);
      }
    }

    // Output for step t-1: designated wave, from its own zbuf (h[t-1]),
    // after the h store -> off the critical path.
    if (t > 0 && gwid == ((t - 1) & 255)) {
      const uint4 wv0 = *(const uint4*)(wlds + 8 * l);
      const uint4 wv1 = *(const uint4*)(wlds + 8 * l + 4);
      const uint4 zv0 = *(const uint4*)(zb + 8 * l);
      const uint4 zv1 = *(const uint4*)(zb + 8 * l + 4);
      float o = 0.f;
      o = fdot2(wv0.x, zv0.x, o);
      o = fdot2(wv0.y, zv0.y, o);
      o = fdot2(wv0.z, zv0.z, o);
      o = fdot2(wv0.w, zv0.w, o);
      o = fdot2(wv1.x, zv1.x, o);
      o = fdot2(wv1.y, zv1.y, o);
      o = fdot2(wv1.z, zv1.z, o);
      o = fdot2(wv1.w, zv1.w, o);
#pragma unroll
      for (int off = 32; off >= 1; off >>= 1) o += __shfl_xor(o, off);
      if (l == 0) out[t - 1] = sigmoidf_(o + b_out0);
    }
  }
}

extern "C" void kernel_launch(void* const* d_in, const int* in_sizes, int n_in,
                              void* d_out, int out_size, void* d_ws, size_t ws_size,
                              hipStream_t stream) {
  const float* seq = (const float*)d_in[0];
  const float* Wih = (const float*)d_in[1];
  const float* Whh = (const float*)d_in[2];
  const float* bih = (const float*)d_in[3];
  const float* bhh = (const float*)d_in[4];
  const float* Wout = (const float*)d_in[5];
  const float* bout = (const float*)d_in[6];

  uint32_t* ring = (uint32_t*)d_ws;  // 2 * 1024 u32 = 8 KB

  // Deterministic ring init (0xAA = tag 2, proven alias-free vs schedule).
  hipMemsetAsync(d_ws, 0xAA, 2 * HDIM * sizeof(uint32_t), stream);

  lstm_persistent<<<NWG, TPB, 0, stream>>>(seq, Wih, Whh, bih, bhh, Wout, bout,
                                           (float*)d_out, ring);
}